// Round 12
// baseline (295.300 us; speedup 1.0000x reference)
//
#include <hip/hip_runtime.h>
#include <hip/hip_bf16.h>

// GATNet: 2x GATConv + 2-layer MLP.
// R11 -> R12: agg2 fused into the MLP GEMM (agg2_mlp_kernel): each block
// aggregates its own 128 nodes (16-lane groups, 8 passes) straight into the
// LDS A-tile (128x136 bf16), then runs the K=128 MFMA loop + 2-layer MLP
// epilogue. Eliminates gb write+read (25.6MB) and one dispatch (9 -> 8).
// LDS 53KB -> 3 blocks/CU = 12 waves/CU for the gather phase (== agg2's
// measured achieved occupancy, so no latency-hiding loss expected).

__device__ __forceinline__ float lrelu(float x){ return x > 0.f ? x : 0.2f*x; }
__device__ __forceinline__ float elu_f(float x){ return x > 0.f ? x : __expf(x) - 1.f; }
__device__ __forceinline__ unsigned short f2bf(float f){
  __hip_bfloat16 h = __float2bfloat16(f);   // RNE
  return *reinterpret_cast<unsigned short*>(&h);
}
__device__ __forceinline__ float bflo(unsigned int u){ return __uint_as_float(u << 16); }
__device__ __forceinline__ float bfhi(unsigned int u){ return __uint_as_float(u & 0xffff0000u); }
__device__ __forceinline__ unsigned int packbf(float a, float b){
  return (unsigned int)f2bf(a) | ((unsigned int)f2bf(b) << 16);
}

typedef __attribute__((ext_vector_type(8))) short bf16x8;
typedef __attribute__((ext_vector_type(4))) float f32x4;

// ---------------- prep: weight transposes + va + zero bucket arrays ----------------
__global__ void prep_kernel(const float* __restrict__ W1, unsigned short* __restrict__ BT1a,
                            unsigned short* __restrict__ BT1b,
                            const float* __restrict__ W2, unsigned short* __restrict__ BT2,
                            const float* __restrict__ Wm1, unsigned short* __restrict__ BT3,
                            const float* __restrict__ a1s, const float* __restrict__ a1d,
                            float* __restrict__ va, int* __restrict__ bcount,
                            int* __restrict__ gcur, int NB){
  int idx = blockIdx.x*256 + threadIdx.x;
  const int S1 = 128*128, S2 = 128*256, S3 = 128*128;
  if (idx < S1){
    int n = idx >> 7, k = idx & 127;
    BT1a[idx] = f2bf(W1[(size_t)k*256 + n]);
    BT1b[idx] = f2bf(W1[(size_t)k*256 + 128 + n]);
  } else if (idx < S1 + S2){
    int j = idx - S1;
    int n = j >> 8, k = j & 255;
    BT2[j] = f2bf(W2[(size_t)k*128 + n]);
  } else if (idx < S1 + S2 + S3){
    int j = idx - S1 - S2;
    int n = j >> 7, k = j & 127;
    BT3[j] = f2bf(Wm1[(size_t)k*128 + n]);
  } else if (idx < S1 + S2 + S3 + 512){
    int j = idx - S1 - S2 - S3;
    int v = j >> 7, k = j & 127;
    const float* avec = (v < 2) ? a1s : a1d;
    int head = v & 1;
    const float* wrow = W1 + (size_t)k*256 + head*128;
    const float* arow = avec + head*128;
    float s = 0.f;
    #pragma unroll 8
    for (int f = 0; f < 128; ++f) s += wrow[f]*arow[f];
    va[j] = s;
  } else if (idx < S1 + S2 + S3 + 512 + 2048){
    int z = idx - (S1 + S2 + S3 + 512);
    if (z < 1024){ if (z < NB) bcount[z] = 0; }
    else { z -= 1024; if (z < NB) gcur[z] = 0; }
  }
}

// ---------------- f2bf + conv1 alpha dots + edge histogram ----------------
__global__ __launch_bounds__(256) void f2bf_hist_kernel(
    const float* __restrict__ x, unsigned short* __restrict__ xb, int N,
    const float* __restrict__ va, float* __restrict__ as1, float* __restrict__ ad1,
    const int* __restrict__ dst, int E, int* __restrict__ bcount, int NB, int nbConv)
{
  __shared__ int h[1024];
  if ((int)blockIdx.x < nbConv){
    int i = blockIdx.x*256 + threadIdx.x;
    int total = N*32;
    float4 v = make_float4(0.f,0.f,0.f,0.f);
    if (i < total){
      v = ((const float4*)x)[i];
      ushort4 u; u.x=f2bf(v.x); u.y=f2bf(v.y); u.z=f2bf(v.z); u.w=f2bf(v.w);
      ((ushort4*)xb)[i] = u;
    }
    int c = (i & 31) << 2;
    float4 vs0 = *(const float4*)(va + c);
    float4 vs1 = *(const float4*)(va + 128 + c);
    float4 vd0 = *(const float4*)(va + 256 + c);
    float4 vd1 = *(const float4*)(va + 384 + c);
    float s0 = v.x*vs0.x + v.y*vs0.y + v.z*vs0.z + v.w*vs0.w;
    float s1 = v.x*vs1.x + v.y*vs1.y + v.z*vs1.z + v.w*vs1.w;
    float d0 = v.x*vd0.x + v.y*vd0.y + v.z*vd0.z + v.w*vd0.w;
    float d1 = v.x*vd1.x + v.y*vd1.y + v.z*vd1.z + v.w*vd1.w;
    #pragma unroll
    for (int m = 1; m <= 16; m <<= 1){
      s0 += __shfl_xor(s0, m); s1 += __shfl_xor(s1, m);
      d0 += __shfl_xor(d0, m); d1 += __shfl_xor(d1, m);
    }
    if ((i & 31) == 0 && i < total){
      int n = i >> 5;
      *(float2*)(as1 + 2*n) = make_float2(s0, s1);
      *(float2*)(ad1 + 2*n) = make_float2(d0, d1);
    }
  } else {
    for (int i = threadIdx.x; i < NB; i += 256) h[i] = 0;
    __syncthreads();
    int b0 = blockIdx.x - nbConv;
    for (int e = b0*256 + threadIdx.x; e < E; e += 64*256)
      atomicAdd(&h[dst[e] >> 6], 1);
    __syncthreads();
    for (int i = threadIdx.x; i < NB; i += 256)
      if (h[i]) atomicAdd(&bcount[i], h[i]);
  }
}

// ---------------- bscatter: redundant LDS scan + aggregated scatter ----------------
__global__ __launch_bounds__(256) void bscatter_kernel(
    const int* __restrict__ src, const int* __restrict__ dst, int E,
    const int* __restrict__ bcount, int* __restrict__ gcur,
    unsigned int* __restrict__ pairs, int* __restrict__ boff, int NB)
{
  __shared__ int h[1024];
  __shared__ int runbase[1024];
  __shared__ int sc[1024];
  const int t = threadIdx.x;

  #pragma unroll
  for (int q = 0; q < 4; ++q){
    int i = t + q*256;
    sc[i] = (i < NB) ? bcount[i] : 0;
  }
  __syncthreads();
  for (int d = 1; d < 1024; d <<= 1){
    int v[4];
    #pragma unroll
    for (int q = 0; q < 4; ++q){
      int idx = t + q*256;
      v[q] = (idx >= d) ? sc[idx - d] : 0;
    }
    __syncthreads();
    #pragma unroll
    for (int q = 0; q < 4; ++q) sc[t + q*256] += v[q];
    __syncthreads();
  }
  if (blockIdx.x == 0){
    for (int i = t; i < NB; i += 256) boff[i] = i ? sc[i-1] : 0;
    if (t == 0) boff[NB] = sc[NB-1];
  }

  const int e0 = blockIdx.x * 4096;
  for (int i = t; i < NB; i += 256) h[i] = 0;
  __syncthreads();
  int myb[16]; unsigned int myw[16];
  #pragma unroll
  for (int q = 0; q < 16; ++q){
    int e = e0 + q*256 + t;
    int b = -1; unsigned int w = 0;
    if (e < E){
      int d = dst[e];
      b = d >> 6;
      w = ((unsigned int)(d & 63) << 26) | (unsigned int)src[e];
      atomicAdd(&h[b], 1);
    }
    myb[q] = b; myw[q] = w;
  }
  __syncthreads();
  for (int i = t; i < NB; i += 256)
    runbase[i] = h[i] ? atomicAdd(&gcur[i], h[i]) : 0;
  __syncthreads();
  for (int i = t; i < NB; i += 256) h[i] = 0;
  __syncthreads();
  #pragma unroll
  for (int q = 0; q < 16; ++q){
    if (myb[q] >= 0){
      int off = atomicAdd(&h[myb[q]], 1);
      int base = myb[q] ? sc[myb[q]-1] : 0;
      pairs[(size_t)base + runbase[myb[q]] + off] = myw[q];
    }
  }
}

__global__ __launch_bounds__(256) void bbuild_kernel(
    const unsigned int* __restrict__ pairs, const int* __restrict__ boff,
    int* __restrict__ rowptr, int* __restrict__ csr, int N)
{
  __shared__ int deg[64], offs[64], cur[64];
  const int b = blockIdx.x;
  const int t = threadIdx.x;
  const int n0 = b << 6;
  const int nNodes = min(64, N - n0);
  const int p0 = boff[b], p1 = boff[b+1];
  const int base = p0 + n0;
  if (t < 64) deg[t] = (t < nNodes) ? 1 : 0;
  __syncthreads();
  for (int i = p0 + t; i < p1; i += 256)
    atomicAdd(&deg[pairs[i] >> 26], 1);
  __syncthreads();
  if (t < 64){
    int x = deg[t];
    #pragma unroll
    for (int d = 1; d < 64; d <<= 1){
      int y = __shfl_up(x, d);
      if (t >= d) x += y;
    }
    offs[t] = x - deg[t];
    cur[t] = 1;
    if (t < nNodes){
      rowptr[n0 + t + 1] = base + x;
      csr[base + x - deg[t]] = n0 + t;
    }
    if (b == 0 && t == 0) rowptr[0] = 0;
  }
  __syncthreads();
  for (int i = p0 + t; i < p1; i += 256){
    unsigned int w = pairs[i];
    int dl = w >> 26;
    int s  = (int)(w & 0x03ffffffu);
    int off = atomicAdd(&cur[dl], 1);
    csr[base + offs[dl] + off] = s;
  }
}

// ---------------- GEMM core: 128x128 tile, BK=64, bf16 MFMA ----------------
__device__ __forceinline__ void gemm_core(
    const unsigned short* __restrict__ A, int lda,
    const unsigned short* __restrict__ BT, int M, int K, int r0,
    unsigned short* a_s, unsigned short* b_s, f32x4 (&acc)[4][4])
{
  const int tid  = threadIdx.x;
  const int lane = tid & 63, wv = tid >> 6;
  const int mh = (wv & 1)*64, nh = (wv >> 1)*64;
  const int l15 = lane & 15, quad = lane >> 4;
  const int srow = tid >> 3, skc = tid & 7;

  #pragma unroll
  for (int i = 0; i < 4; ++i)
    #pragma unroll
    for (int j = 0; j < 4; ++j)
      #pragma unroll
      for (int r = 0; r < 4; ++r) acc[i][j][r] = 0.f;

  for (int k0 = 0; k0 < K; k0 += 64){
    #pragma unroll
    for (int it = 0; it < 4; ++it){
      int row = it*32 + srow;
      int grow = r0 + row;
      uint4 v = make_uint4(0u,0u,0u,0u);
      if (grow < M) v = *(const uint4*)(A + (size_t)grow*lda + k0 + skc*8);
      *(uint4*)(&a_s[row*72 + skc*8]) = v;
    }
    #pragma unroll
    for (int it = 0; it < 4; ++it){
      int row = it*32 + srow;
      uint4 v = *(const uint4*)(BT + (size_t)row*K + k0 + skc*8);
      *(uint4*)(&b_s[row*72 + skc*8]) = v;
    }
    __syncthreads();
    #pragma unroll
    for (int ks = 0; ks < 64; ks += 32){
      bf16x8 af[4], bfr[4];
      #pragma unroll
      for (int i = 0; i < 4; ++i)
        af[i] = *(const bf16x8*)(&a_s[(mh + i*16 + l15)*72 + ks + quad*8]);
      #pragma unroll
      for (int j = 0; j < 4; ++j)
        bfr[j] = *(const bf16x8*)(&b_s[(nh + j*16 + l15)*72 + ks + quad*8]);
      #pragma unroll
      for (int i = 0; i < 4; ++i)
        #pragma unroll
        for (int j = 0; j < 4; ++j)
          acc[i][j] = __builtin_amdgcn_mfma_f32_16x16x32_bf16(bfr[j], af[i], acc[i][j], 0, 0, 0);
    }
    __syncthreads();
  }
}

__global__ __launch_bounds__(256) void gemm_conv1_kernel(
    const unsigned short* __restrict__ xa, const unsigned short* __restrict__ BT1a,
    const unsigned short* __restrict__ BT1b, unsigned short* __restrict__ out1b,
    int M, const float* __restrict__ b1)
{
  __shared__ unsigned short a_s[128*72];
  __shared__ unsigned short b_s[128*72];
  const int hx = blockIdx.x;
  const unsigned short* A  = xa + hx*128;
  const unsigned short* BT = hx ? BT1b : BT1a;
  unsigned short* C = out1b + hx*128;
  const float* bias = b1 + hx*128;
  const int r0 = blockIdx.y*128;
  f32x4 acc[4][4];
  gemm_core(A, 256, BT, M, 128, r0, a_s, b_s, acc);

  const int lane = threadIdx.x & 63, wv = threadIdx.x >> 6;
  const int mh = (wv & 1)*64, nh = (wv >> 1)*64;
  const int l15 = lane & 15, quad = lane >> 4;
  #pragma unroll
  for (int i = 0; i < 4; ++i){
    int m = r0 + mh + i*16 + l15;
    if (m < M){
      #pragma unroll
      for (int j = 0; j < 4; ++j){
        int n = nh + j*16 + quad*4;
        float4 bb = *(const float4*)(bias + n);
        ushort4 u;
        u.x = f2bf(elu_f(acc[i][j][0] + bb.x));
        u.y = f2bf(elu_f(acc[i][j][1] + bb.y));
        u.z = f2bf(elu_f(acc[i][j][2] + bb.z));
        u.w = f2bf(elu_f(acc[i][j][3] + bb.w));
        *(ushort4*)(C + (size_t)m*256 + n) = u;
      }
    }
  }
}

__global__ __launch_bounds__(256) void gemm_conv2_kernel(
    const unsigned short* __restrict__ out1b, const unsigned short* __restrict__ BT2,
    unsigned short* __restrict__ h2b, int M,
    const float* __restrict__ a2s, const float* __restrict__ a2d,
    float* __restrict__ as2, float* __restrict__ ad2)
{
  __shared__ unsigned short a_s[128*72];
  __shared__ unsigned short b_s[128*72];
  __shared__ float part_s[128][2];
  __shared__ float part_d[128][2];
  const int r0 = blockIdx.y*128;
  f32x4 acc[4][4];
  gemm_core(out1b, 256, BT2, M, 256, r0, a_s, b_s, acc);

  const int tid = threadIdx.x;
  const int lane = tid & 63, wv = tid >> 6;
  const int mh = (wv & 1)*64, nh = (wv >> 1)*64;
  const int l15 = lane & 15, quad = lane >> 4;
  #pragma unroll
  for (int i = 0; i < 4; ++i){
    int m = r0 + mh + i*16 + l15;
    float ps = 0.f, pd = 0.f;
    #pragma unroll
    for (int j = 0; j < 4; ++j){
      int n = nh + j*16 + quad*4;
      float4 wsv = *(const float4*)(a2s + n);
      float4 wdv = *(const float4*)(a2d + n);
      float v0 = acc[i][j][0], v1 = acc[i][j][1], v2 = acc[i][j][2], v3 = acc[i][j][3];
      ps += v0*wsv.x + v1*wsv.y + v2*wsv.z + v3*wsv.w;
      pd += v0*wdv.x + v1*wdv.y + v2*wdv.z + v3*wdv.w;
      if (m < M){
        ushort4 u;
        u.x = f2bf(v0); u.y = f2bf(v1); u.z = f2bf(v2); u.w = f2bf(v3);
        *(ushort4*)(h2b + (size_t)m*128 + n) = u;
      }
    }
    ps += __shfl_xor(ps, 16); ps += __shfl_xor(ps, 32);
    pd += __shfl_xor(pd, 16); pd += __shfl_xor(pd, 32);
    if (quad == 0){
      part_s[mh + i*16 + l15][wv >> 1] = ps;
      part_d[mh + i*16 + l15][wv >> 1] = pd;
    }
  }
  __syncthreads();
  if (tid < 128){
    int gm = r0 + tid;
    if (gm < M){
      as2[gm] = part_s[tid][0] + part_s[tid][1];
      ad2[gm] = part_d[tid][0] + part_d[tid][1];
    }
  }
}

// ---------------- fused agg2 + MLP GEMM + MLP layer 2 ----------------
// Block handles nodes r0..r0+127: phase 1 aggregates them (agg2) straight
// into the LDS A-tile (128x136 bf16); phase 2 = K=128 MFMA + MLP epilogue.
__global__ __launch_bounds__(256) void agg2_mlp_kernel(
    const unsigned short* __restrict__ h2b, const float* __restrict__ as_,
    const float* __restrict__ ad_, const int* __restrict__ rowptr,
    const int* __restrict__ csr, const float* __restrict__ b2,
    const unsigned short* __restrict__ BT3, int N, const float* __restrict__ bm1,
    const float* __restrict__ Wm2, const float* __restrict__ bm2,
    float* __restrict__ out)
{
  __shared__ unsigned short a_s[128*136];   // 34,816 B (A-tile, stride 136)
  __shared__ unsigned short b_s[128*72];    // 18,432 B (B-tile; reused for wm2/part)
  const int tid = threadIdx.x;
  const int wv = tid >> 6, lane = tid & 63;
  const int ql = lane & 15;
  const int grp = wv*4 + (lane >> 4);       // 0..15
  const int r0 = blockIdx.x*128;

  // ---- phase 1: agg2 for this block's 128 nodes, 8 passes x 16 nodes ----
  for (int pass = 0; pass < 8; ++pass){
    const int row = pass*16 + grp;
    const int n = r0 + row;
    const bool valid = n < N;
    int start = 0, end = 0;
    float adn = 0.f;
    if (valid){ start = rowptr[n]; end = rowptr[n+1]; adn = ad_[n]; }

    int jl = start + ql;
    bool have = valid && (jl < end);
    int s_l = 0;
    float p_l = 0.f;
    if (have){
      s_l = csr[jl];
      p_l = __expf(lrelu(as_[s_l] + adn));
    }
    float l = p_l;
    for (int j = jl + 16; j < end; j += 16)
      l += __expf(lrelu(as_[csr[j]] + adn));
    #pragma unroll
    for (int msk = 1; msk <= 8; msk <<= 1) l += __shfl_xor(l, msk);
    float inv = 1.f / fmaxf(l, 1e-16f);
    float a_l = p_l * inv;

    float acc[8];
    #pragma unroll
    for (int i = 0; i < 8; ++i) acc[i] = 0.f;
    const int c = ql << 3;
    const unsigned short* hp = h2b + c;

    int cnt = valid ? min(16, end - start) : 0;
    int t = 0;
    for (; t + 3 < cnt; t += 4){
      int   sA = __shfl(s_l, t, 16),   sB = __shfl(s_l, t+1, 16);
      int   sC = __shfl(s_l, t+2, 16), sD = __shfl(s_l, t+3, 16);
      float aA = __shfl(a_l, t, 16),   aB = __shfl(a_l, t+1, 16);
      float aC = __shfl(a_l, t+2, 16), aD = __shfl(a_l, t+3, 16);
      uint4 uA = *(const uint4*)(hp + (sA << 7));
      uint4 uB = *(const uint4*)(hp + (sB << 7));
      uint4 uC = *(const uint4*)(hp + (sC << 7));
      uint4 uD = *(const uint4*)(hp + (sD << 7));
      float fA[8] = {bflo(uA.x),bfhi(uA.x),bflo(uA.y),bfhi(uA.y),bflo(uA.z),bfhi(uA.z),bflo(uA.w),bfhi(uA.w)};
      float fB[8] = {bflo(uB.x),bfhi(uB.x),bflo(uB.y),bfhi(uB.y),bflo(uB.z),bfhi(uB.z),bflo(uB.w),bfhi(uB.w)};
      float fC[8] = {bflo(uC.x),bfhi(uC.x),bflo(uC.y),bfhi(uC.y),bflo(uC.z),bfhi(uC.z),bflo(uC.w),bfhi(uC.w)};
      float fD[8] = {bflo(uD.x),bfhi(uD.x),bflo(uD.y),bfhi(uD.y),bflo(uD.z),bfhi(uD.z),bflo(uD.w),bfhi(uD.w)};
      #pragma unroll
      for (int i = 0; i < 8; ++i)
        acc[i] += aA*fA[i] + aB*fB[i] + aC*fC[i] + aD*fD[i];
    }
    for (; t < cnt; ++t){
      int   sA = __shfl(s_l, t, 16);
      float aA = __shfl(a_l, t, 16);
      uint4 u = *(const uint4*)(hp + (sA << 7));
      float fA[8] = {bflo(u.x),bfhi(u.x),bflo(u.y),bfhi(u.y),bflo(u.z),bfhi(u.z),bflo(u.w),bfhi(u.w)};
      #pragma unroll
      for (int i = 0; i < 8; ++i) acc[i] += aA*fA[i];
    }
    for (int jb = start + 16; jb < end; jb += 16){
      int jl2 = jb + ql;
      int s2 = 0; float a2 = 0.f;
      if (jl2 < end){
        s2 = csr[jl2];
        a2 = __expf(lrelu(as_[s2] + adn)) * inv;
      }
      int cnt2 = min(16, end - jb);
      for (int t2 = 0; t2 < cnt2; ++t2){
        int   sA = __shfl(s2, t2, 16);
        float aA = __shfl(a2, t2, 16);
        uint4 u = *(const uint4*)(hp + (sA << 7));
        float fA[8] = {bflo(u.x),bfhi(u.x),bflo(u.y),bfhi(u.y),bflo(u.z),bfhi(u.z),bflo(u.w),bfhi(u.w)};
        #pragma unroll
        for (int i = 0; i < 8; ++i) acc[i] += aA*fA[i];
      }
    }

    uint4 up = make_uint4(0u,0u,0u,0u);
    if (valid){
      float4 bb0 = *(const float4*)(b2 + c);
      float4 bb1 = *(const float4*)(b2 + c + 4);
      float o[8];
      o[0]=elu_f(acc[0]+bb0.x); o[1]=elu_f(acc[1]+bb0.y);
      o[2]=elu_f(acc[2]+bb0.z); o[3]=elu_f(acc[3]+bb0.w);
      o[4]=elu_f(acc[4]+bb1.x); o[5]=elu_f(acc[5]+bb1.y);
      o[6]=elu_f(acc[6]+bb1.z); o[7]=elu_f(acc[7]+bb1.w);
      up.x = packbf(o[0], o[1]); up.y = packbf(o[2], o[3]);
      up.z = packbf(o[4], o[5]); up.w = packbf(o[6], o[7]);
    }
    *(uint4*)(&a_s[row*136 + c]) = up;     // bf16 row into LDS A-tile
  }
  __syncthreads();

  // ---- phase 2: GEMM K=128, A from LDS, B staged; then MLP layer 2 ----
  const int mh = (wv & 1)*64, nh = (wv >> 1)*64;
  const int l15 = lane & 15, quad = lane >> 4;
  const int srow = tid >> 3, skc = tid & 7;
  f32x4 acc[4][4];
  #pragma unroll
  for (int i = 0; i < 4; ++i)
    #pragma unroll
    for (int j = 0; j < 4; ++j)
      #pragma unroll
      for (int r = 0; r < 4; ++r) acc[i][j][r] = 0.f;

  for (int k0 = 0; k0 < 128; k0 += 64){
    #pragma unroll
    for (int it = 0; it < 4; ++it){
      int rowb = it*32 + srow;
      uint4 v = *(const uint4*)(BT3 + (size_t)rowb*128 + k0 + skc*8);
      *(uint4*)(&b_s[rowb*72 + skc*8]) = v;
    }
    __syncthreads();
    #pragma unroll
    for (int ks = 0; ks < 64; ks += 32){
      bf16x8 af[4], bfr[4];
      #pragma unroll
      for (int i = 0; i < 4; ++i)
        af[i] = *(const bf16x8*)(&a_s[(mh + i*16 + l15)*136 + k0 + ks + quad*8]);
      #pragma unroll
      for (int j = 0; j < 4; ++j)
        bfr[j] = *(const bf16x8*)(&b_s[(nh + j*16 + l15)*72 + ks + quad*8]);
      #pragma unroll
      for (int i = 0; i < 4; ++i)
        #pragma unroll
        for (int j = 0; j < 4; ++j)
          acc[i][j] = __builtin_amdgcn_mfma_f32_16x16x32_bf16(bfr[j], af[i], acc[i][j], 0, 0, 0);
    }
    __syncthreads();
  }

  // overlay wm2 + partials onto b_s (dead after K-loop; sync above done)
  float* wm2_s = (float*)b_s;            // 1024 floats
  float* part  = ((float*)b_s) + 1024;   // 2048 floats
  {
    int i4 = tid*4;
    *(float4*)(&wm2_s[i4]) = *(const float4*)(Wm2 + i4);
  }
  __syncthreads();
  #pragma unroll
  for (int i = 0; i < 4; ++i){
    float po[8];
    #pragma unroll
    for (int o = 0; o < 8; ++o) po[o] = 0.f;
    #pragma unroll
    for (int j = 0; j < 4; ++j){
      int n = nh + j*16 + quad*4;
      float4 bb = *(const float4*)(bm1 + n);
      #pragma unroll
      for (int r = 0; r < 4; ++r){
        float hcol = fmaxf(acc[i][j][r] + ((const float*)&bb)[r], 0.f);
        const float* wr = &wm2_s[(n + r)*8];
        #pragma unroll
        for (int o = 0; o < 8; ++o) po[o] += hcol*wr[o];
      }
    }
    #pragma unroll
    for (int o = 0; o < 8; ++o){
      po[o] += __shfl_xor(po[o], 16);
      po[o] += __shfl_xor(po[o], 32);
    }
    if (quad == 0){
      #pragma unroll
      for (int o = 0; o < 8; ++o)
        part[(mh + i*16 + l15)*16 + (wv >> 1)*8 + o] = po[o];
    }
  }
  __syncthreads();
  if (tid < 128){
    int gm = r0 + tid;
    if (gm < N){
      float4 o0, o1;
      o0.x = fmaxf(part[tid*16 + 0] + part[tid*16 + 8]  + bm2[0], 0.f);
      o0.y = fmaxf(part[tid*16 + 1] + part[tid*16 + 9]  + bm2[1], 0.f);
      o0.z = fmaxf(part[tid*16 + 2] + part[tid*16 + 10] + bm2[2], 0.f);
      o0.w = fmaxf(part[tid*16 + 3] + part[tid*16 + 11] + bm2[3], 0.f);
      o1.x = fmaxf(part[tid*16 + 4] + part[tid*16 + 12] + bm2[4], 0.f);
      o1.y = fmaxf(part[tid*16 + 5] + part[tid*16 + 13] + bm2[5], 0.f);
      o1.z = fmaxf(part[tid*16 + 6] + part[tid*16 + 14] + bm2[6], 0.f);
      o1.w = fmaxf(part[tid*16 + 7] + part[tid*16 + 15] + bm2[7], 0.f);
      *(float4*)(out + (size_t)gm*8)     = o0;
      *(float4*)(out + (size_t)gm*8 + 4) = o1;
    }
  }
}

// ---------------- agg1x: 4 nodes/wave, 16 lanes/node, unroll-4 gather ----------------
__global__ __launch_bounds__(256) void agg1x_kernel(
    const unsigned short* __restrict__ xb, const float* __restrict__ as_,
    const float* __restrict__ ad_, const int* __restrict__ rowptr, const int* __restrict__ csr,
    unsigned short* __restrict__ xa, int N)
{
  const int wv = threadIdx.x >> 6, lane = threadIdx.x & 63;
  const int ql = lane & 15;
  const int n = blockIdx.x*16 + wv*4 + (lane >> 4);
  const bool valid = n < N;
  int start = 0, end = 0;
  float2 adv = make_float2(0.f, 0.f);
  if (valid){ start = rowptr[n]; end = rowptr[n+1]; adv = *(const float2*)(ad_ + 2*n); }

  int jl = start + ql;
  bool have = valid && (jl < end);
  int s_l = 0;
  float p0 = 0.f, p1 = 0.f;
  if (have){
    s_l = csr[jl];
    float2 av = *(const float2*)(as_ + 2*s_l);
    p0 = __expf(lrelu(av.x + adv.x));
    p1 = __expf(lrelu(av.y + adv.y));
  }
  float l0 = p0, l1 = p1;
  for (int j = jl + 16; j < end; j += 16){
    int s = csr[j];
    float2 av = *(const float2*)(as_ + 2*s);
    l0 += __expf(lrelu(av.x + adv.x));
    l1 += __expf(lrelu(av.y + adv.y));
  }
  #pragma unroll
  for (int msk = 1; msk <= 8; msk <<= 1){
    l0 += __shfl_xor(l0, msk);
    l1 += __shfl_xor(l1, msk);
  }
  float inv0 = 1.f / fmaxf(l0, 1e-16f);
  float inv1 = 1.f / fmaxf(l1, 1e-16f);
  float a0_l = p0 * inv0;
  float a1_l = p1 * inv1;

  float acc0[8], acc1[8];
  #pragma unroll
  for (int i = 0; i < 8; ++i){ acc0[i] = 0.f; acc1[i] = 0.f; }
  const int c = ql << 3;
  const unsigned short* hp = xb + c;

  int cnt = valid ? min(16, end - start) : 0;
  int t = 0;
  for (; t + 3 < cnt; t += 4){
    int   sA  = __shfl(s_l, t, 16),    sB  = __shfl(s_l, t+1, 16);
    int   sC  = __shfl(s_l, t+2, 16),  sD  = __shfl(s_l, t+3, 16);
    float a0A = __shfl(a0_l, t, 16),   a0B = __shfl(a0_l, t+1, 16);
    float a0C = __shfl(a0_l, t+2, 16), a0D = __shfl(a0_l, t+3, 16);
    float a1A = __shfl(a1_l, t, 16),   a1B = __shfl(a1_l, t+1, 16);
    float a1C = __shfl(a1_l, t+2, 16), a1D = __shfl(a1_l, t+3, 16);
    uint4 uA = *(const uint4*)(hp + (sA << 7));
    uint4 uB = *(const uint4*)(hp + (sB << 7));
    uint4 uC = *(const uint4*)(hp + (sC << 7));
    uint4 uD = *(const uint4*)(hp + (sD << 7));
    float fA[8] = {bflo(uA.x),bfhi(uA.x),bflo(uA.y),bfhi(uA.y),bflo(uA.z),bfhi(uA.z),bflo(uA.w),bfhi(uA.w)};
    float fB[8] = {bflo(uB.x),bfhi(uB.x),bflo(uB.y),bfhi(uB.y),bflo(uB.z),bfhi(uB.z),bflo(uB.w),bfhi(uB.w)};
    float fC[8] = {bflo(uC.x),bfhi(uC.x),bflo(uC.y),bfhi(uC.y),bflo(uC.z),bfhi(uC.z),bflo(uC.w),bfhi(uC.w)};
    float fD[8] = {bflo(uD.x),bfhi(uD.x),bflo(uD.y),bfhi(uD.y),bflo(uD.z),bfhi(uD.z),bflo(uD.w),bfhi(uD.w)};
    #pragma unroll
    for (int i = 0; i < 8; ++i){
      acc0[i] += a0A*fA[i] + a0B*fB[i] + a0C*fC[i] + a0D*fD[i];
      acc1[i] += a1A*fA[i] + a1B*fB[i] + a1C*fC[i] + a1D*fD[i];
    }
  }
  for (; t < cnt; ++t){
    int   sA  = __shfl(s_l, t, 16);
    float a0A = __shfl(a0_l, t, 16);
    float a1A = __shfl(a1_l, t, 16);
    uint4 u = *(const uint4*)(hp + (sA << 7));
    float fA[8] = {bflo(u.x),bfhi(u.x),bflo(u.y),bfhi(u.y),bflo(u.z),bfhi(u.z),bflo(u.w),bfhi(u.w)};
    #pragma unroll
    for (int i = 0; i < 8; ++i){
      acc0[i] += a0A*fA[i];
      acc1[i] += a1A*fA[i];
    }
  }
  for (int jb = start + 16; jb < end; jb += 16){
    int jl2 = jb + ql;
    int s2 = 0; float a0_2 = 0.f, a1_2 = 0.f;
    if (jl2 < end){
      s2 = csr[jl2];
      float2 av = *(const float2*)(as_ + 2*s2);
      a0_2 = __expf(lrelu(av.x + adv.x)) * inv0;
      a1_2 = __expf(lrelu(av.y + adv.y)) * inv1;
    }
    int cnt2 = min(16, end - jb);
    for (int t2 = 0; t2 < cnt2; ++t2){
      int   sA  = __shfl(s2, t2, 16);
      float a0A = __shfl(a0_2, t2, 16);
      float a1A = __shfl(a1_2, t2, 16);
      uint4 u = *(const uint4*)(hp + (sA << 7));
      float fA[8] = {bflo(u.x),bfhi(u.x),bflo(u.y),bfhi(u.y),bflo(u.z),bfhi(u.z),bflo(u.w),bfhi(u.w)};
      #pragma unroll
      for (int i = 0; i < 8; ++i){
        acc0[i] += a0A*fA[i];
        acc1[i] += a1A*fA[i];
      }
    }
  }

  if (valid){
    uint4 u0, u1;
    u0.x = packbf(acc0[0], acc0[1]); u0.y = packbf(acc0[2], acc0[3]);
    u0.z = packbf(acc0[4], acc0[5]); u0.w = packbf(acc0[6], acc0[7]);
    u1.x = packbf(acc1[0], acc1[1]); u1.y = packbf(acc1[2], acc1[3]);
    u1.z = packbf(acc1[4], acc1[5]); u1.w = packbf(acc1[6], acc1[7]);
    *(uint4*)(xa + (size_t)n*256 + c)       = u0;
    *(uint4*)(xa + (size_t)n*256 + 128 + c) = u1;
  }
}

extern "C" void kernel_launch(void* const* d_in, const int* in_sizes, int n_in,
                              void* d_out, int out_size, void* d_ws, size_t ws_size,
                              hipStream_t stream)
{
  (void)n_in; (void)out_size; (void)ws_size;
  const float* x   = (const float*)d_in[0];
  const int*   ei  = (const int*)d_in[1];
  const float* W1  = (const float*)d_in[2];
  const float* a1s = (const float*)d_in[3];
  const float* a1d = (const float*)d_in[4];
  const float* b1  = (const float*)d_in[5];
  const float* W2  = (const float*)d_in[6];
  const float* a2s = (const float*)d_in[7];
  const float* a2d = (const float*)d_in[8];
  const float* b2  = (const float*)d_in[9];
  const float* Wm1 = (const float*)d_in[10];
  const float* bm1 = (const float*)d_in[11];
  const float* Wm2 = (const float*)d_in[12];
  const float* bm2 = (const float*)d_in[13];
  float* out = (float*)d_out;

  const int N = in_sizes[0] / 128;
  const int E = in_sizes[1] / 2;
  const int NB = (N + 63) >> 6;
  const int* srcp = ei;
  const int* dstp = ei + E;

  char* ws = (char*)d_ws;
  unsigned short* xb    = (unsigned short*)ws;
  unsigned short* xa    = (unsigned short*)(ws + (size_t)N*256);
  unsigned short* out1b = (unsigned short*)(ws + (size_t)N*768);
  unsigned short* h2b   = (unsigned short*)(ws + (size_t)N*1280);
  char* tail = ws + (size_t)N*1536;
  unsigned short* BT1a = (unsigned short*)tail;
  unsigned short* BT1b = BT1a + 128*128;
  unsigned short* BT2  = BT1b + 128*128;
  unsigned short* BT3  = BT2 + 128*256;
  float* va   = (float*)(BT3 + 128*128);
  float* as1  = va + 512;
  float* ad1  = as1 + (size_t)2*N;
  float* as2  = ad1 + (size_t)2*N;
  float* ad2  = as2 + N;
  int* bcount = (int*)(ad2 + N);
  int* boff   = bcount + 1024;
  int* gcur   = boff + 1032;
  int* rowptr = gcur + 1024;
  int* csr    = rowptr + N + 1;
  unsigned int* pairs = (unsigned int*)(csr + E + N);

  const int nbConv = (N*32 + 255)/256;
  const int prepTotal = 128*128 + 128*256 + 128*128 + 512 + 2048;

  // 1: prep
  prep_kernel<<<(prepTotal + 255)/256, 256, 0, stream>>>(
      W1, BT1a, BT1b, W2, BT2, Wm1, BT3, a1s, a1d, va, bcount, gcur, NB);
  // 2: x convert + conv1 alpha dots + edge histogram
  f2bf_hist_kernel<<<nbConv + 64, 256, 0, stream>>>(x, xb, N, va, as1, ad1,
                                                    dstp, E, bcount, NB, nbConv);
  // 3: bucket scatter (scan fused per-block; block 0 publishes boff)
  bscatter_kernel<<<(E + 4095)/4096, 256, 0, stream>>>(srcp, dstp, E, bcount, gcur,
                                                       pairs, boff, NB);
  // 4: per-bucket CSR build
  bbuild_kernel<<<NB, 256, 0, stream>>>(pairs, boff, rowptr, csr, N);

  const int gy   = (N + 127) / 128;
  const int nb16 = (N + 15) / 16;

  // 5-8: main pipeline
  agg1x_kernel<<<nb16, 256, 0, stream>>>(xb, as1, ad1, rowptr, csr, xa, N);
  gemm_conv1_kernel<<<dim3(2, gy), 256, 0, stream>>>(xa, BT1a, BT1b, out1b, N, b1);
  gemm_conv2_kernel<<<dim3(1, gy), 256, 0, stream>>>(out1b, BT2, h2b, N, a2s, a2d, as2, ad2);
  agg2_mlp_kernel<<<gy, 256, 0, stream>>>(h2b, as2, ad2, rowptr, csr, b2,
                                          BT3, N, bm1, Wm2, bm2, out);
}

// Round 13
// 274.817 us; speedup vs baseline: 1.0745x; 1.0745x over previous
//
#include <hip/hip_runtime.h>
#include <hip/hip_bf16.h>

// GATNet: 2x GATConv + 2-layer MLP.
// R12 -> R13: revert to R11 (267us), then fuse the MLP into agg2 KEEPING
// AGG2'S GRID (3125 blocks x 16 nodes) -- R12 failed because the fused kernel
// used the GEMM's 391-block grid, collapsing the latency-bound gather's
// parallelism 8x. Here: phase 1 = R11 agg2 verbatim, 16 bf16 rows -> LDS;
// phase 2 = per-wave 16x32 MFMA (K=128, BT3 from L2) + relu + MLP layer 2
// (Wm2 in LDS) -> writes d_out. Removes gb 25.6MB round-trip + 1 dispatch.

__device__ __forceinline__ float lrelu(float x){ return x > 0.f ? x : 0.2f*x; }
__device__ __forceinline__ float elu_f(float x){ return x > 0.f ? x : __expf(x) - 1.f; }
__device__ __forceinline__ unsigned short f2bf(float f){
  __hip_bfloat16 h = __float2bfloat16(f);   // RNE
  return *reinterpret_cast<unsigned short*>(&h);
}
__device__ __forceinline__ float bflo(unsigned int u){ return __uint_as_float(u << 16); }
__device__ __forceinline__ float bfhi(unsigned int u){ return __uint_as_float(u & 0xffff0000u); }
__device__ __forceinline__ unsigned int packbf(float a, float b){
  return (unsigned int)f2bf(a) | ((unsigned int)f2bf(b) << 16);
}

typedef __attribute__((ext_vector_type(8))) short bf16x8;
typedef __attribute__((ext_vector_type(4))) float f32x4;

// ---------------- prep: weight transposes + va + zero bucket arrays ----------------
__global__ void prep_kernel(const float* __restrict__ W1, unsigned short* __restrict__ BT1a,
                            unsigned short* __restrict__ BT1b,
                            const float* __restrict__ W2, unsigned short* __restrict__ BT2,
                            const float* __restrict__ Wm1, unsigned short* __restrict__ BT3,
                            const float* __restrict__ a1s, const float* __restrict__ a1d,
                            float* __restrict__ va, int* __restrict__ bcount,
                            int* __restrict__ gcur, int NB){
  int idx = blockIdx.x*256 + threadIdx.x;
  const int S1 = 128*128, S2 = 128*256, S3 = 128*128;
  if (idx < S1){
    int n = idx >> 7, k = idx & 127;
    BT1a[idx] = f2bf(W1[(size_t)k*256 + n]);
    BT1b[idx] = f2bf(W1[(size_t)k*256 + 128 + n]);
  } else if (idx < S1 + S2){
    int j = idx - S1;
    int n = j >> 8, k = j & 255;
    BT2[j] = f2bf(W2[(size_t)k*128 + n]);
  } else if (idx < S1 + S2 + S3){
    int j = idx - S1 - S2;
    int n = j >> 7, k = j & 127;
    BT3[j] = f2bf(Wm1[(size_t)k*128 + n]);
  } else if (idx < S1 + S2 + S3 + 512){
    int j = idx - S1 - S2 - S3;
    int v = j >> 7, k = j & 127;
    const float* avec = (v < 2) ? a1s : a1d;
    int head = v & 1;
    const float* wrow = W1 + (size_t)k*256 + head*128;
    const float* arow = avec + head*128;
    float s = 0.f;
    #pragma unroll 8
    for (int f = 0; f < 128; ++f) s += wrow[f]*arow[f];
    va[j] = s;
  } else if (idx < S1 + S2 + S3 + 512 + 2048){
    int z = idx - (S1 + S2 + S3 + 512);
    if (z < 1024){ if (z < NB) bcount[z] = 0; }
    else { z -= 1024; if (z < NB) gcur[z] = 0; }
  }
}

// ---------------- f2bf + conv1 alpha dots + edge histogram ----------------
__global__ __launch_bounds__(256) void f2bf_hist_kernel(
    const float* __restrict__ x, unsigned short* __restrict__ xb, int N,
    const float* __restrict__ va, float* __restrict__ as1, float* __restrict__ ad1,
    const int* __restrict__ dst, int E, int* __restrict__ bcount, int NB, int nbConv)
{
  __shared__ int h[1024];
  if ((int)blockIdx.x < nbConv){
    int i = blockIdx.x*256 + threadIdx.x;
    int total = N*32;
    float4 v = make_float4(0.f,0.f,0.f,0.f);
    if (i < total){
      v = ((const float4*)x)[i];
      ushort4 u; u.x=f2bf(v.x); u.y=f2bf(v.y); u.z=f2bf(v.z); u.w=f2bf(v.w);
      ((ushort4*)xb)[i] = u;
    }
    int c = (i & 31) << 2;
    float4 vs0 = *(const float4*)(va + c);
    float4 vs1 = *(const float4*)(va + 128 + c);
    float4 vd0 = *(const float4*)(va + 256 + c);
    float4 vd1 = *(const float4*)(va + 384 + c);
    float s0 = v.x*vs0.x + v.y*vs0.y + v.z*vs0.z + v.w*vs0.w;
    float s1 = v.x*vs1.x + v.y*vs1.y + v.z*vs1.z + v.w*vs1.w;
    float d0 = v.x*vd0.x + v.y*vd0.y + v.z*vd0.z + v.w*vd0.w;
    float d1 = v.x*vd1.x + v.y*vd1.y + v.z*vd1.z + v.w*vd1.w;
    #pragma unroll
    for (int m = 1; m <= 16; m <<= 1){
      s0 += __shfl_xor(s0, m); s1 += __shfl_xor(s1, m);
      d0 += __shfl_xor(d0, m); d1 += __shfl_xor(d1, m);
    }
    if ((i & 31) == 0 && i < total){
      int n = i >> 5;
      *(float2*)(as1 + 2*n) = make_float2(s0, s1);
      *(float2*)(ad1 + 2*n) = make_float2(d0, d1);
    }
  } else {
    for (int i = threadIdx.x; i < NB; i += 256) h[i] = 0;
    __syncthreads();
    int b0 = blockIdx.x - nbConv;
    for (int e = b0*256 + threadIdx.x; e < E; e += 64*256)
      atomicAdd(&h[dst[e] >> 6], 1);
    __syncthreads();
    for (int i = threadIdx.x; i < NB; i += 256)
      if (h[i]) atomicAdd(&bcount[i], h[i]);
  }
}

// ---------------- bscatter: redundant LDS scan + aggregated scatter ----------------
__global__ __launch_bounds__(256) void bscatter_kernel(
    const int* __restrict__ src, const int* __restrict__ dst, int E,
    const int* __restrict__ bcount, int* __restrict__ gcur,
    unsigned int* __restrict__ pairs, int* __restrict__ boff, int NB)
{
  __shared__ int h[1024];
  __shared__ int runbase[1024];
  __shared__ int sc[1024];
  const int t = threadIdx.x;

  #pragma unroll
  for (int q = 0; q < 4; ++q){
    int i = t + q*256;
    sc[i] = (i < NB) ? bcount[i] : 0;
  }
  __syncthreads();
  for (int d = 1; d < 1024; d <<= 1){
    int v[4];
    #pragma unroll
    for (int q = 0; q < 4; ++q){
      int idx = t + q*256;
      v[q] = (idx >= d) ? sc[idx - d] : 0;
    }
    __syncthreads();
    #pragma unroll
    for (int q = 0; q < 4; ++q) sc[t + q*256] += v[q];
    __syncthreads();
  }
  if (blockIdx.x == 0){
    for (int i = t; i < NB; i += 256) boff[i] = i ? sc[i-1] : 0;
    if (t == 0) boff[NB] = sc[NB-1];
  }

  const int e0 = blockIdx.x * 4096;
  for (int i = t; i < NB; i += 256) h[i] = 0;
  __syncthreads();
  int myb[16]; unsigned int myw[16];
  #pragma unroll
  for (int q = 0; q < 16; ++q){
    int e = e0 + q*256 + t;
    int b = -1; unsigned int w = 0;
    if (e < E){
      int d = dst[e];
      b = d >> 6;
      w = ((unsigned int)(d & 63) << 26) | (unsigned int)src[e];
      atomicAdd(&h[b], 1);
    }
    myb[q] = b; myw[q] = w;
  }
  __syncthreads();
  for (int i = t; i < NB; i += 256)
    runbase[i] = h[i] ? atomicAdd(&gcur[i], h[i]) : 0;
  __syncthreads();
  for (int i = t; i < NB; i += 256) h[i] = 0;
  __syncthreads();
  #pragma unroll
  for (int q = 0; q < 16; ++q){
    if (myb[q] >= 0){
      int off = atomicAdd(&h[myb[q]], 1);
      int base = myb[q] ? sc[myb[q]-1] : 0;
      pairs[(size_t)base + runbase[myb[q]] + off] = myw[q];
    }
  }
}

__global__ __launch_bounds__(256) void bbuild_kernel(
    const unsigned int* __restrict__ pairs, const int* __restrict__ boff,
    int* __restrict__ rowptr, int* __restrict__ csr, int N)
{
  __shared__ int deg[64], offs[64], cur[64];
  const int b = blockIdx.x;
  const int t = threadIdx.x;
  const int n0 = b << 6;
  const int nNodes = min(64, N - n0);
  const int p0 = boff[b], p1 = boff[b+1];
  const int base = p0 + n0;
  if (t < 64) deg[t] = (t < nNodes) ? 1 : 0;
  __syncthreads();
  for (int i = p0 + t; i < p1; i += 256)
    atomicAdd(&deg[pairs[i] >> 26], 1);
  __syncthreads();
  if (t < 64){
    int x = deg[t];
    #pragma unroll
    for (int d = 1; d < 64; d <<= 1){
      int y = __shfl_up(x, d);
      if (t >= d) x += y;
    }
    offs[t] = x - deg[t];
    cur[t] = 1;
    if (t < nNodes){
      rowptr[n0 + t + 1] = base + x;
      csr[base + x - deg[t]] = n0 + t;
    }
    if (b == 0 && t == 0) rowptr[0] = 0;
  }
  __syncthreads();
  for (int i = p0 + t; i < p1; i += 256){
    unsigned int w = pairs[i];
    int dl = w >> 26;
    int s  = (int)(w & 0x03ffffffu);
    int off = atomicAdd(&cur[dl], 1);
    csr[base + offs[dl] + off] = s;
  }
}

// ---------------- GEMM core: 128x128 tile, BK=64, bf16 MFMA ----------------
__device__ __forceinline__ void gemm_core(
    const unsigned short* __restrict__ A, int lda,
    const unsigned short* __restrict__ BT, int M, int K, int r0,
    unsigned short* a_s, unsigned short* b_s, f32x4 (&acc)[4][4])
{
  const int tid  = threadIdx.x;
  const int lane = tid & 63, wv = tid >> 6;
  const int mh = (wv & 1)*64, nh = (wv >> 1)*64;
  const int l15 = lane & 15, quad = lane >> 4;
  const int srow = tid >> 3, skc = tid & 7;

  #pragma unroll
  for (int i = 0; i < 4; ++i)
    #pragma unroll
    for (int j = 0; j < 4; ++j)
      #pragma unroll
      for (int r = 0; r < 4; ++r) acc[i][j][r] = 0.f;

  for (int k0 = 0; k0 < K; k0 += 64){
    #pragma unroll
    for (int it = 0; it < 4; ++it){
      int row = it*32 + srow;
      int grow = r0 + row;
      uint4 v = make_uint4(0u,0u,0u,0u);
      if (grow < M) v = *(const uint4*)(A + (size_t)grow*lda + k0 + skc*8);
      *(uint4*)(&a_s[row*72 + skc*8]) = v;
    }
    #pragma unroll
    for (int it = 0; it < 4; ++it){
      int row = it*32 + srow;
      uint4 v = *(const uint4*)(BT + (size_t)row*K + k0 + skc*8);
      *(uint4*)(&b_s[row*72 + skc*8]) = v;
    }
    __syncthreads();
    #pragma unroll
    for (int ks = 0; ks < 64; ks += 32){
      bf16x8 af[4], bfr[4];
      #pragma unroll
      for (int i = 0; i < 4; ++i)
        af[i] = *(const bf16x8*)(&a_s[(mh + i*16 + l15)*72 + ks + quad*8]);
      #pragma unroll
      for (int j = 0; j < 4; ++j)
        bfr[j] = *(const bf16x8*)(&b_s[(nh + j*16 + l15)*72 + ks + quad*8]);
      #pragma unroll
      for (int i = 0; i < 4; ++i)
        #pragma unroll
        for (int j = 0; j < 4; ++j)
          acc[i][j] = __builtin_amdgcn_mfma_f32_16x16x32_bf16(bfr[j], af[i], acc[i][j], 0, 0, 0);
    }
    __syncthreads();
  }
}

__global__ __launch_bounds__(256) void gemm_conv1_kernel(
    const unsigned short* __restrict__ xa, const unsigned short* __restrict__ BT1a,
    const unsigned short* __restrict__ BT1b, unsigned short* __restrict__ out1b,
    int M, const float* __restrict__ b1)
{
  __shared__ unsigned short a_s[128*72];
  __shared__ unsigned short b_s[128*72];
  const int hx = blockIdx.x;
  const unsigned short* A  = xa + hx*128;
  const unsigned short* BT = hx ? BT1b : BT1a;
  unsigned short* C = out1b + hx*128;
  const float* bias = b1 + hx*128;
  const int r0 = blockIdx.y*128;
  f32x4 acc[4][4];
  gemm_core(A, 256, BT, M, 128, r0, a_s, b_s, acc);

  const int lane = threadIdx.x & 63, wv = threadIdx.x >> 6;
  const int mh = (wv & 1)*64, nh = (wv >> 1)*64;
  const int l15 = lane & 15, quad = lane >> 4;
  #pragma unroll
  for (int i = 0; i < 4; ++i){
    int m = r0 + mh + i*16 + l15;
    if (m < M){
      #pragma unroll
      for (int j = 0; j < 4; ++j){
        int n = nh + j*16 + quad*4;
        float4 bb = *(const float4*)(bias + n);
        ushort4 u;
        u.x = f2bf(elu_f(acc[i][j][0] + bb.x));
        u.y = f2bf(elu_f(acc[i][j][1] + bb.y));
        u.z = f2bf(elu_f(acc[i][j][2] + bb.z));
        u.w = f2bf(elu_f(acc[i][j][3] + bb.w));
        *(ushort4*)(C + (size_t)m*256 + n) = u;
      }
    }
  }
}

__global__ __launch_bounds__(256) void gemm_conv2_kernel(
    const unsigned short* __restrict__ out1b, const unsigned short* __restrict__ BT2,
    unsigned short* __restrict__ h2b, int M,
    const float* __restrict__ a2s, const float* __restrict__ a2d,
    float* __restrict__ as2, float* __restrict__ ad2)
{
  __shared__ unsigned short a_s[128*72];
  __shared__ unsigned short b_s[128*72];
  __shared__ float part_s[128][2];
  __shared__ float part_d[128][2];
  const int r0 = blockIdx.y*128;
  f32x4 acc[4][4];
  gemm_core(out1b, 256, BT2, M, 256, r0, a_s, b_s, acc);

  const int tid = threadIdx.x;
  const int lane = tid & 63, wv = tid >> 6;
  const int mh = (wv & 1)*64, nh = (wv >> 1)*64;
  const int l15 = lane & 15, quad = lane >> 4;
  #pragma unroll
  for (int i = 0; i < 4; ++i){
    int m = r0 + mh + i*16 + l15;
    float ps = 0.f, pd = 0.f;
    #pragma unroll
    for (int j = 0; j < 4; ++j){
      int n = nh + j*16 + quad*4;
      float4 wsv = *(const float4*)(a2s + n);
      float4 wdv = *(const float4*)(a2d + n);
      float v0 = acc[i][j][0], v1 = acc[i][j][1], v2 = acc[i][j][2], v3 = acc[i][j][3];
      ps += v0*wsv.x + v1*wsv.y + v2*wsv.z + v3*wsv.w;
      pd += v0*wdv.x + v1*wdv.y + v2*wdv.z + v3*wdv.w;
      if (m < M){
        ushort4 u;
        u.x = f2bf(v0); u.y = f2bf(v1); u.z = f2bf(v2); u.w = f2bf(v3);
        *(ushort4*)(h2b + (size_t)m*128 + n) = u;
      }
    }
    ps += __shfl_xor(ps, 16); ps += __shfl_xor(ps, 32);
    pd += __shfl_xor(pd, 16); pd += __shfl_xor(pd, 32);
    if (quad == 0){
      part_s[mh + i*16 + l15][wv >> 1] = ps;
      part_d[mh + i*16 + l15][wv >> 1] = pd;
    }
  }
  __syncthreads();
  if (tid < 128){
    int gm = r0 + tid;
    if (gm < M){
      as2[gm] = part_s[tid][0] + part_s[tid][1];
      ad2[gm] = part_d[tid][0] + part_d[tid][1];
    }
  }
}

// ---------------- agg1x: 4 nodes/wave, 16 lanes/node, unroll-4 gather ----------------
__global__ __launch_bounds__(256) void agg1x_kernel(
    const unsigned short* __restrict__ xb, const float* __restrict__ as_,
    const float* __restrict__ ad_, const int* __restrict__ rowptr, const int* __restrict__ csr,
    unsigned short* __restrict__ xa, int N)
{
  const int wv = threadIdx.x >> 6, lane = threadIdx.x & 63;
  const int ql = lane & 15;
  const int n = blockIdx.x*16 + wv*4 + (lane >> 4);
  const bool valid = n < N;
  int start = 0, end = 0;
  float2 adv = make_float2(0.f, 0.f);
  if (valid){ start = rowptr[n]; end = rowptr[n+1]; adv = *(const float2*)(ad_ + 2*n); }

  int jl = start + ql;
  bool have = valid && (jl < end);
  int s_l = 0;
  float p0 = 0.f, p1 = 0.f;
  if (have){
    s_l = csr[jl];
    float2 av = *(const float2*)(as_ + 2*s_l);
    p0 = __expf(lrelu(av.x + adv.x));
    p1 = __expf(lrelu(av.y + adv.y));
  }
  float l0 = p0, l1 = p1;
  for (int j = jl + 16; j < end; j += 16){
    int s = csr[j];
    float2 av = *(const float2*)(as_ + 2*s);
    l0 += __expf(lrelu(av.x + adv.x));
    l1 += __expf(lrelu(av.y + adv.y));
  }
  #pragma unroll
  for (int msk = 1; msk <= 8; msk <<= 1){
    l0 += __shfl_xor(l0, msk);
    l1 += __shfl_xor(l1, msk);
  }
  float inv0 = 1.f / fmaxf(l0, 1e-16f);
  float inv1 = 1.f / fmaxf(l1, 1e-16f);
  float a0_l = p0 * inv0;
  float a1_l = p1 * inv1;

  float acc0[8], acc1[8];
  #pragma unroll
  for (int i = 0; i < 8; ++i){ acc0[i] = 0.f; acc1[i] = 0.f; }
  const int c = ql << 3;
  const unsigned short* hp = xb + c;

  int cnt = valid ? min(16, end - start) : 0;
  int t = 0;
  for (; t + 3 < cnt; t += 4){
    int   sA  = __shfl(s_l, t, 16),    sB  = __shfl(s_l, t+1, 16);
    int   sC  = __shfl(s_l, t+2, 16),  sD  = __shfl(s_l, t+3, 16);
    float a0A = __shfl(a0_l, t, 16),   a0B = __shfl(a0_l, t+1, 16);
    float a0C = __shfl(a0_l, t+2, 16), a0D = __shfl(a0_l, t+3, 16);
    float a1A = __shfl(a1_l, t, 16),   a1B = __shfl(a1_l, t+1, 16);
    float a1C = __shfl(a1_l, t+2, 16), a1D = __shfl(a1_l, t+3, 16);
    uint4 uA = *(const uint4*)(hp + (sA << 7));
    uint4 uB = *(const uint4*)(hp + (sB << 7));
    uint4 uC = *(const uint4*)(hp + (sC << 7));
    uint4 uD = *(const uint4*)(hp + (sD << 7));
    float fA[8] = {bflo(uA.x),bfhi(uA.x),bflo(uA.y),bfhi(uA.y),bflo(uA.z),bfhi(uA.z),bflo(uA.w),bfhi(uA.w)};
    float fB[8] = {bflo(uB.x),bfhi(uB.x),bflo(uB.y),bfhi(uB.y),bflo(uB.z),bfhi(uB.z),bflo(uB.w),bfhi(uB.w)};
    float fC[8] = {bflo(uC.x),bfhi(uC.x),bflo(uC.y),bfhi(uC.y),bflo(uC.z),bfhi(uC.z),bflo(uC.w),bfhi(uC.w)};
    float fD[8] = {bflo(uD.x),bfhi(uD.x),bflo(uD.y),bfhi(uD.y),bflo(uD.z),bfhi(uD.z),bflo(uD.w),bfhi(uD.w)};
    #pragma unroll
    for (int i = 0; i < 8; ++i){
      acc0[i] += a0A*fA[i] + a0B*fB[i] + a0C*fC[i] + a0D*fD[i];
      acc1[i] += a1A*fA[i] + a1B*fB[i] + a1C*fC[i] + a1D*fD[i];
    }
  }
  for (; t < cnt; ++t){
    int   sA  = __shfl(s_l, t, 16);
    float a0A = __shfl(a0_l, t, 16);
    float a1A = __shfl(a1_l, t, 16);
    uint4 u = *(const uint4*)(hp + (sA << 7));
    float fA[8] = {bflo(u.x),bfhi(u.x),bflo(u.y),bfhi(u.y),bflo(u.z),bfhi(u.z),bflo(u.w),bfhi(u.w)};
    #pragma unroll
    for (int i = 0; i < 8; ++i){
      acc0[i] += a0A*fA[i];
      acc1[i] += a1A*fA[i];
    }
  }
  for (int jb = start + 16; jb < end; jb += 16){
    int jl2 = jb + ql;
    int s2 = 0; float a0_2 = 0.f, a1_2 = 0.f;
    if (jl2 < end){
      s2 = csr[jl2];
      float2 av = *(const float2*)(as_ + 2*s2);
      a0_2 = __expf(lrelu(av.x + adv.x)) * inv0;
      a1_2 = __expf(lrelu(av.y + adv.y)) * inv1;
    }
    int cnt2 = min(16, end - jb);
    for (int t2 = 0; t2 < cnt2; ++t2){
      int   sA  = __shfl(s2, t2, 16);
      float a0A = __shfl(a0_2, t2, 16);
      float a1A = __shfl(a1_2, t2, 16);
      uint4 u = *(const uint4*)(hp + (sA << 7));
      float fA[8] = {bflo(u.x),bfhi(u.x),bflo(u.y),bfhi(u.y),bflo(u.z),bfhi(u.z),bflo(u.w),bfhi(u.w)};
      #pragma unroll
      for (int i = 0; i < 8; ++i){
        acc0[i] += a0A*fA[i];
        acc1[i] += a1A*fA[i];
      }
    }
  }

  if (valid){
    uint4 u0, u1;
    u0.x = packbf(acc0[0], acc0[1]); u0.y = packbf(acc0[2], acc0[3]);
    u0.z = packbf(acc0[4], acc0[5]); u0.w = packbf(acc0[6], acc0[7]);
    u1.x = packbf(acc1[0], acc1[1]); u1.y = packbf(acc1[2], acc1[3]);
    u1.z = packbf(acc1[4], acc1[5]); u1.w = packbf(acc1[6], acc1[7]);
    *(uint4*)(xa + (size_t)n*256 + c)       = u0;
    *(uint4*)(xa + (size_t)n*256 + 128 + c) = u1;
  }
}

// ---------------- agg2 + MLP fused, AGG2'S GRID (16 nodes/block) ----------------
// Phase 1: R11 agg2 for the block's 16 nodes -> bf16 rows in LDS g_s[16][136].
// Phase 2: per-wave 16x32 MFMA vs BT3 (K=128) + bm1/relu -> h_s[16][132] fp32.
// Phase 3: layer 2 (Wm2 in LDS): tid=(node,o,kg), 64-MAC partial + shfl.
__global__ __launch_bounds__(256) void agg2_mlp_kernel(
    const unsigned short* __restrict__ h2b, const float* __restrict__ as_,
    const float* __restrict__ ad_, const int* __restrict__ rowptr,
    const int* __restrict__ csr, const float* __restrict__ b2,
    const unsigned short* __restrict__ BT3, int N, const float* __restrict__ bm1,
    const float* __restrict__ Wm2, const float* __restrict__ bm2,
    float* __restrict__ out)
{
  __shared__ unsigned short g_s[16*136];   // 4,352 B bf16
  __shared__ float h_s[16*132];            // 8,448 B fp32
  __shared__ float wm2_s[128*8];           // 4,096 B
  const int tid = threadIdx.x;
  const int wv = tid >> 6, lane = tid & 63;
  const int ql = lane & 15;
  const int grp = wv*4 + (lane >> 4);      // 0..15 (node row in block)
  const int n = blockIdx.x*16 + grp;
  const bool valid = n < N;

  // stage Wm2 (independent of phase 1)
  {
    int i4 = tid*4;
    *(float4*)(&wm2_s[i4]) = *(const float4*)(Wm2 + i4);
  }

  // ---- phase 1: agg2 (identical math to R11) ----
  int start = 0, end = 0;
  float adn = 0.f;
  if (valid){ start = rowptr[n]; end = rowptr[n+1]; adn = ad_[n]; }

  int jl = start + ql;
  bool have = valid && (jl < end);
  int s_l = 0;
  float p_l = 0.f;
  if (have){
    s_l = csr[jl];
    p_l = __expf(lrelu(as_[s_l] + adn));
  }
  float l = p_l;
  for (int j = jl + 16; j < end; j += 16)
    l += __expf(lrelu(as_[csr[j]] + adn));
  #pragma unroll
  for (int msk = 1; msk <= 8; msk <<= 1) l += __shfl_xor(l, msk);
  float inv = 1.f / fmaxf(l, 1e-16f);
  float a_l = p_l * inv;

  float acc[8];
  #pragma unroll
  for (int i = 0; i < 8; ++i) acc[i] = 0.f;
  const int c = ql << 3;
  const unsigned short* hp = h2b + c;

  int cnt = valid ? min(16, end - start) : 0;
  int t = 0;
  for (; t + 3 < cnt; t += 4){
    int   sA = __shfl(s_l, t, 16),   sB = __shfl(s_l, t+1, 16);
    int   sC = __shfl(s_l, t+2, 16), sD = __shfl(s_l, t+3, 16);
    float aA = __shfl(a_l, t, 16),   aB = __shfl(a_l, t+1, 16);
    float aC = __shfl(a_l, t+2, 16), aD = __shfl(a_l, t+3, 16);
    uint4 uA = *(const uint4*)(hp + (sA << 7));
    uint4 uB = *(const uint4*)(hp + (sB << 7));
    uint4 uC = *(const uint4*)(hp + (sC << 7));
    uint4 uD = *(const uint4*)(hp + (sD << 7));
    float fA[8] = {bflo(uA.x),bfhi(uA.x),bflo(uA.y),bfhi(uA.y),bflo(uA.z),bfhi(uA.z),bflo(uA.w),bfhi(uA.w)};
    float fB[8] = {bflo(uB.x),bfhi(uB.x),bflo(uB.y),bfhi(uB.y),bflo(uB.z),bfhi(uB.z),bflo(uB.w),bfhi(uB.w)};
    float fC[8] = {bflo(uC.x),bfhi(uC.x),bflo(uC.y),bfhi(uC.y),bflo(uC.z),bfhi(uC.z),bflo(uC.w),bfhi(uC.w)};
    float fD[8] = {bflo(uD.x),bfhi(uD.x),bflo(uD.y),bfhi(uD.y),bflo(uD.z),bfhi(uD.z),bflo(uD.w),bfhi(uD.w)};
    #pragma unroll
    for (int i = 0; i < 8; ++i)
      acc[i] += aA*fA[i] + aB*fB[i] + aC*fC[i] + aD*fD[i];
  }
  for (; t < cnt; ++t){
    int   sA = __shfl(s_l, t, 16);
    float aA = __shfl(a_l, t, 16);
    uint4 u = *(const uint4*)(hp + (sA << 7));
    float fA[8] = {bflo(u.x),bfhi(u.x),bflo(u.y),bfhi(u.y),bflo(u.z),bfhi(u.z),bflo(u.w),bfhi(u.w)};
    #pragma unroll
    for (int i = 0; i < 8; ++i) acc[i] += aA*fA[i];
  }
  for (int jb = start + 16; jb < end; jb += 16){
    int jl2 = jb + ql;
    int s2 = 0; float a2 = 0.f;
    if (jl2 < end){
      s2 = csr[jl2];
      a2 = __expf(lrelu(as_[s2] + adn)) * inv;
    }
    int cnt2 = min(16, end - jb);
    for (int t2 = 0; t2 < cnt2; ++t2){
      int   sA = __shfl(s2, t2, 16);
      float aA = __shfl(a2, t2, 16);
      uint4 u = *(const uint4*)(hp + (sA << 7));
      float fA[8] = {bflo(u.x),bfhi(u.x),bflo(u.y),bfhi(u.y),bflo(u.z),bfhi(u.z),bflo(u.w),bfhi(u.w)};
      #pragma unroll
      for (int i = 0; i < 8; ++i) acc[i] += aA*fA[i];
    }
  }

  uint4 up = make_uint4(0u,0u,0u,0u);
  if (valid){
    float4 bb0 = *(const float4*)(b2 + c);
    float4 bb1 = *(const float4*)(b2 + c + 4);
    float o[8];
    o[0]=elu_f(acc[0]+bb0.x); o[1]=elu_f(acc[1]+bb0.y);
    o[2]=elu_f(acc[2]+bb0.z); o[3]=elu_f(acc[3]+bb0.w);
    o[4]=elu_f(acc[4]+bb1.x); o[5]=elu_f(acc[5]+bb1.y);
    o[6]=elu_f(acc[6]+bb1.z); o[7]=elu_f(acc[7]+bb1.w);
    up.x = packbf(o[0], o[1]); up.y = packbf(o[2], o[3]);
    up.z = packbf(o[4], o[5]); up.w = packbf(o[6], o[7]);
  }
  *(uint4*)(&g_s[grp*136 + c]) = up;       // bf16 row (zeros if invalid)
  __syncthreads();

  // ---- phase 2: wave wv computes h cols n2 = wv*32 .. +31 (K=128 MFMA) ----
  const int l15 = lane & 15, quad = lane >> 4;
  f32x4 macc[2];
  #pragma unroll
  for (int j = 0; j < 2; ++j)
    #pragma unroll
    for (int r = 0; r < 4; ++r) macc[j][r] = 0.f;
  #pragma unroll
  for (int ks = 0; ks < 128; ks += 32){
    bf16x8 af = *(const bf16x8*)(&g_s[l15*136 + ks + quad*8]);
    #pragma unroll
    for (int j = 0; j < 2; ++j){
      int n2 = wv*32 + j*16 + l15;
      bf16x8 bf = *(const bf16x8*)(BT3 + (size_t)n2*128 + ks + quad*8);
      macc[j] = __builtin_amdgcn_mfma_f32_16x16x32_bf16(bf, af, macc[j], 0, 0, 0);
    }
  }
  // D: col m = l15, row n2 = wv*32 + j*16 + quad*4 + r
  #pragma unroll
  for (int j = 0; j < 2; ++j){
    #pragma unroll
    for (int r = 0; r < 4; ++r){
      int n2 = wv*32 + j*16 + quad*4 + r;
      h_s[l15*132 + n2] = fmaxf(macc[j][r] + bm1[n2], 0.f);
    }
  }
  __syncthreads();

  // ---- phase 3: out[node][o] = relu(h . Wm2[:,o] + bm2[o]) ----
  {
    const int node = tid >> 4;              // 0..15
    const int rem  = tid & 15;
    const int o    = rem >> 1;              // 0..7
    const int kg   = rem & 1;               // 0..1
    const float* hrow = &h_s[node*132 + kg*64];
    float po = 0.f;
    #pragma unroll 16
    for (int k = 0; k < 64; ++k) po += hrow[k] * wm2_s[(kg*64 + k)*8 + o];
    po += __shfl_xor(po, 1);
    int gm = blockIdx.x*16 + node;
    if (kg == 0 && gm < N)
      out[(size_t)gm*8 + o] = fmaxf(po + bm2[o], 0.f);
  }
}

extern "C" void kernel_launch(void* const* d_in, const int* in_sizes, int n_in,
                              void* d_out, int out_size, void* d_ws, size_t ws_size,
                              hipStream_t stream)
{
  (void)n_in; (void)out_size; (void)ws_size;
  const float* x   = (const float*)d_in[0];
  const int*   ei  = (const int*)d_in[1];
  const float* W1  = (const float*)d_in[2];
  const float* a1s = (const float*)d_in[3];
  const float* a1d = (const float*)d_in[4];
  const float* b1  = (const float*)d_in[5];
  const float* W2  = (const float*)d_in[6];
  const float* a2s = (const float*)d_in[7];
  const float* a2d = (const float*)d_in[8];
  const float* b2  = (const float*)d_in[9];
  const float* Wm1 = (const float*)d_in[10];
  const float* bm1 = (const float*)d_in[11];
  const float* Wm2 = (const float*)d_in[12];
  const float* bm2 = (const float*)d_in[13];
  float* out = (float*)d_out;

  const int N = in_sizes[0] / 128;
  const int E = in_sizes[1] / 2;
  const int NB = (N + 63) >> 6;
  const int* srcp = ei;
  const int* dstp = ei + E;

  char* ws = (char*)d_ws;
  unsigned short* xb    = (unsigned short*)ws;
  unsigned short* xa    = (unsigned short*)(ws + (size_t)N*256);
  unsigned short* out1b = (unsigned short*)(ws + (size_t)N*768);
  unsigned short* h2b   = (unsigned short*)(ws + (size_t)N*1280);
  char* tail = ws + (size_t)N*1536;
  unsigned short* BT1a = (unsigned short*)tail;
  unsigned short* BT1b = BT1a + 128*128;
  unsigned short* BT2  = BT1b + 128*128;
  unsigned short* BT3  = BT2 + 128*256;
  float* va   = (float*)(BT3 + 128*128);
  float* as1  = va + 512;
  float* ad1  = as1 + (size_t)2*N;
  float* as2  = ad1 + (size_t)2*N;
  float* ad2  = as2 + N;
  int* bcount = (int*)(ad2 + N);
  int* boff   = bcount + 1024;
  int* gcur   = boff + 1032;
  int* rowptr = gcur + 1024;
  int* csr    = rowptr + N + 1;
  unsigned int* pairs = (unsigned int*)(csr + E + N);

  const int nbConv = (N*32 + 255)/256;
  const int prepTotal = 128*128 + 128*256 + 128*128 + 512 + 2048;

  // 1: prep
  prep_kernel<<<(prepTotal + 255)/256, 256, 0, stream>>>(
      W1, BT1a, BT1b, W2, BT2, Wm1, BT3, a1s, a1d, va, bcount, gcur, NB);
  // 2: x convert + conv1 alpha dots + edge histogram
  f2bf_hist_kernel<<<nbConv + 64, 256, 0, stream>>>(x, xb, N, va, as1, ad1,
                                                    dstp, E, bcount, NB, nbConv);
  // 3: bucket scatter (scan fused per-block; block 0 publishes boff)
  bscatter_kernel<<<(E + 4095)/4096, 256, 0, stream>>>(srcp, dstp, E, bcount, gcur,
                                                       pairs, boff, NB);
  // 4: per-bucket CSR build
  bbuild_kernel<<<NB, 256, 0, stream>>>(pairs, boff, rowptr, csr, N);

  const int gy   = (N + 127) / 128;
  const int nb16 = (N + 15) / 16;

  // 5-8: main pipeline
  agg1x_kernel<<<nb16, 256, 0, stream>>>(xb, as1, ad1, rowptr, csr, xa, N);
  gemm_conv1_kernel<<<dim3(2, gy), 256, 0, stream>>>(xa, BT1a, BT1b, out1b, N, b1);
  gemm_conv2_kernel<<<dim3(1, gy), 256, 0, stream>>>(out1b, BT2, h2b, N, a2s, a2d, as2, ad2);
  agg2_mlp_kernel<<<nb16, 256, 0, stream>>>(h2b, as2, ad2, rowptr, csr, b2,
                                            BT3, N, bm1, Wm2, bm2, out);
}